// Round 8
// baseline (386.555 us; speedup 1.0000x reference)
//
#include <hip/hip_runtime.h>
#include <math.h>

#define CDIM 32
#define HWDIM 2304            // 48*48
#define BDIM 16
#define PPW 8                 // pixels per wave (8 lanes per pixel)
#define NTHREADS 256          // 4 waves => 32 pixels per block
#define PPB 32
#define CROWS 128             // rc-rows per chunk (16 KB)
#define NCHUNK 8
#define NBUF 3
#define ZOFF (BDIM * CDIM * HWDIM)   // z elements, then 16 logdet floats

// R7 lesson: DPP broadcasts landed (VALUBusy 13->25%) but dur only
// 130->114us: the wall is dependency bubbles with just 2 waves/SIMD to
// interleave them (HBM 10%, conflicts 0). R8: occupancy 2->3 waves/SIMD
// (launch_bounds(256,3); 3 blocks/CU x 48KB LDS = 144 <= 160). To help the
// ~170-reg/thread budget fit, x-loads are deferred from the prologue to the
// last stage call (c==4), shortening y[4]'s live range; they are then the 4
// newest vmcnt entries, so the tail drains become vmcnt(12)/(8)/(4) at
// c=5/6/7 (entry-outstanding 16/12/8, oldest-first retire) and vmcnt(0)
// before y-elimination. WRITE_SIZE is the spill tripwire.
__device__ __forceinline__ void gload_lds16(const float* g, float* l) {
    __builtin_amdgcn_global_load_lds(
        (const __attribute__((address_space(1))) float*)g,
        (__attribute__((address_space(3))) float*)l, 16, 0, 0);
}

// Broadcast the value held by lane (group_base + k7) to all 8 lanes of each
// aligned 8-lane group. k7 must be compile-time (call sites fully unrolled).
// Step1: quad_perm([s,s,s,s]), s=k7&3 -> every quad holds its own lane s.
// Step2: copy across the quad pair of each 8-group (bank-traced, R7):
//   k7<4 : value in even quads -> row_shr:4 (dst[i]=src[i-4]) mask 0xA
//   k7>=4: value in odd quads  -> row_shl:4 (dst[i]=src[i+4]) mask 0x5
__device__ __forceinline__ float bcast8(float x, int k7) {
    int v = __float_as_int(x), b;
    switch (k7) {
    case 0: b = __builtin_amdgcn_update_dpp(v, v, 0x00, 0xF, 0xF, false);
            b = __builtin_amdgcn_update_dpp(b, b, 0x114, 0xF, 0xA, false); break;
    case 1: b = __builtin_amdgcn_update_dpp(v, v, 0x55, 0xF, 0xF, false);
            b = __builtin_amdgcn_update_dpp(b, b, 0x114, 0xF, 0xA, false); break;
    case 2: b = __builtin_amdgcn_update_dpp(v, v, 0xAA, 0xF, 0xF, false);
            b = __builtin_amdgcn_update_dpp(b, b, 0x114, 0xF, 0xA, false); break;
    case 3: b = __builtin_amdgcn_update_dpp(v, v, 0xFF, 0xF, 0xF, false);
            b = __builtin_amdgcn_update_dpp(b, b, 0x114, 0xF, 0xA, false); break;
    case 4: b = __builtin_amdgcn_update_dpp(v, v, 0x00, 0xF, 0xF, false);
            b = __builtin_amdgcn_update_dpp(b, b, 0x104, 0xF, 0x5, false); break;
    case 5: b = __builtin_amdgcn_update_dpp(v, v, 0x55, 0xF, 0xF, false);
            b = __builtin_amdgcn_update_dpp(b, b, 0x104, 0xF, 0x5, false); break;
    case 6: b = __builtin_amdgcn_update_dpp(v, v, 0xAA, 0xF, 0xF, false);
            b = __builtin_amdgcn_update_dpp(b, b, 0x104, 0xF, 0x5, false); break;
    default: b = __builtin_amdgcn_update_dpp(v, v, 0xFF, 0xF, 0xF, false);
            b = __builtin_amdgcn_update_dpp(b, b, 0x104, 0xF, 0x5, false); break;
    }
    return __int_as_float(b);
}

__global__ __launch_bounds__(NTHREADS, 3)
void solve_kernel(const float* __restrict__ input,
                  const float* __restrict__ weight,
                  const float* __restrict__ logdet,
                  float* __restrict__ out) {
    const int t    = threadIdx.x;
    const int lane = t & 63;
    const int wv   = t >> 6;           // wave 0..3
    const int h    = lane & 7;         // row class: owns rows i = 8q + h
    const int p    = lane >> 3;        // pixel-in-wave 0..7

    const int blk  = blockIdx.x;
    const int b    = blk / (HWDIM / PPB);       // 72 blocks per batch image
    const int pb   = (blk % (HWDIM / PPB)) * PPB;  // block pixel base
    const int pixl = wv * PPW + p;              // pixel-in-block 0..31
    const int pix0 = pb + wv * PPW;             // wave pixel base (logdet cond)
    const int pix  = pb + pixl;

    __shared__ float lds[NBUF][CROWS * CDIM];   // 3 x 16KB ring

    // ---- DMA staging: chunk c = columns [4c,4c+4) x 32 rows x 32 pixels ----
    // Chunk-local row rl = i*4 + jo (i = matrix row, jo = col-in-chunk);
    // rc-row = i*32 + 4c + jo. Wave wv stages rl in [32wv,32wv+32): per call
    // q, lane (sg,sp) covers rl = 32wv+8q+sg, 16B slot sp. LDS dest linear
    // (word rl*32 + sp*4); global source slot pre-swizzled by g = i&7
    // (constant across a rc-row's 8 lanes -> full 128B line, permuted).
    // Read side: A[q][4c+jo] at word rl*32 + ((ps^h)<<2) + pc; worst-case
    // 2-way bank aliasing = free.
    const int sg = lane >> 3;
    const int sp = lane & 7;
    const int ps = pixl >> 2, pc = pixl & 3;
    const float* wbase = weight + (size_t)b * (CDIM * CDIM) * HWDIM + pb;

    auto stage = [&](int c, int buf) {
        float* lbase = &lds[buf][(wv * 32) * CDIM];
        #pragma unroll
        for (int q = 0; q < 4; ++q) {
            const int rl = wv * 32 + q * 8 + sg;
            const int i_ = rl >> 2, jo = rl & 3, g = i_ & 7;
            const float* s = wbase + (size_t)(i_ * 32 + 4 * c + jo) * HWDIM
                                   + ((sp ^ g) << 2);
            gload_lds16(s, lbase + q * 8 * CDIM);
        }
    };

    stage(0, 0);
    asm volatile("" ::: "memory");
    stage(1, 1);
    asm volatile("" ::: "memory");
    stage(2, 2);

    float A[4][CDIM];
    float y[4];
    float lacc = 0.0f;

    #pragma unroll
    for (int c = 0; c < NCHUNK; ++c) {
        // retire chunk c's 4 DMAs; keep later chunks (and, after c==4, the
        // 4 x-loads) in flight. Entry-outstanding: c<=4: 12; c==5: 16;
        // c==6: 12; c==7: 8 (oldest-first retire).
        if (c < 5)       asm volatile("s_waitcnt vmcnt(8)" ::: "memory");
        else if (c == 5) asm volatile("s_waitcnt vmcnt(12)" ::: "memory");
        else if (c == 6) asm volatile("s_waitcnt vmcnt(8)" ::: "memory");
        else             asm volatile("s_waitcnt vmcnt(4)" ::: "memory");
        __builtin_amdgcn_s_barrier();
        asm volatile("" ::: "memory");

        // read this chunk's 16 entries: A[q][4c+jo] = W[8q+h][4c+jo] @ pixl
        #pragma unroll
        for (int q = 0; q < 4; ++q)
            #pragma unroll
            for (int jo = 0; jo < 4; ++jo)
                A[q][4 * c + jo] =
                    lds[c % NBUF][((8 * q + h) * 4 + jo) * CDIM
                                  + ((ps ^ h) << 2) + pc];

        if (c <= 4) {
            // all waves done reading buf c%3 -> safe to overwrite with c+3;
            // issue the DMA BEFORE the long compute so it hides under it.
            asm volatile("s_waitcnt lgkmcnt(0)" ::: "memory");
            __builtin_amdgcn_s_barrier();
            asm volatile("" ::: "memory");
            stage(c + 3, c % NBUF);
            if (c == 4) {
                // deferred x-loads: newest 4 vmcnt entries from here on
                const float* xp = input + (size_t)b * CDIM * HWDIM
                                        + (size_t)h * HWDIM + pix;
                #pragma unroll
                for (int r = 0; r < 4; ++r) y[r] = xp[(size_t)(r * 8) * HWDIM];
                asm volatile("" ::: "memory");
            }
        }

        // ---- left-looking: update+factor columns 4c..4c+3 ----
        #pragma unroll
        for (int jo = 0; jo < 4; ++jo) {
            const int j = 4 * c + jo;
            #pragma unroll
            for (int k = 0; k < j; ++k) {
                const int trk = k >> 3, k7 = k & 7;
                float bv = bcast8(A[trk][j], k7);
                // slot trk: below rows use stored m; owner uses (1-r) ->
                // A -= (1-r)A = rA (the scaling); above rows: no-op.
                float mk = (h >= k7) ? A[trk][k] : 0.0f;
                A[trk][j] = fmaf(-mk, bv, A[trk][j]);
                #pragma unroll
                for (int q = trk + 1; q < 4; ++q)
                    A[q][j] = fmaf(-A[q][k], bv, A[q][j]);
            }
            // pivot j: column j is fully eliminated; store L in place.
            const int trj = j >> 3, j7 = j & 7;
            float bp = bcast8(A[trj][j], j7);
            float rr = __builtin_amdgcn_rcpf(bp);
            lacc += __log2f(fabsf(bp));
            A[trj][j] = (h > j7) ? A[trj][j] * rr
                                 : ((h == j7) ? (1.0f - rr) : A[trj][j]);
            #pragma unroll
            for (int q = trj + 1; q < 4; ++q) A[q][j] *= rr;
        }
    }

    // x-loads complete before y-elimination uses them.
    asm volatile("s_waitcnt vmcnt(0)" ::: "memory");

    // ---- forward-eliminate y with stored L (same masking as columns) ----
    #pragma unroll
    for (int k = 0; k < CDIM; ++k) {
        const int tr = k >> 3, k7 = k & 7;
        float bq = bcast8(y[tr], k7);
        float mk = (h >= k7) ? A[tr][k] : 0.0f;
        y[tr] = fmaf(-mk, bq, y[tr]);
        #pragma unroll
        for (int q = tr + 1; q < 4; ++q) y[q] = fmaf(-A[q][k], bq, y[q]);
    }

    // ---- back-substitution (U has unit diagonal; reads only U entries) ----
    #pragma unroll
    for (int k = CDIM - 1; k >= 1; --k) {
        const int tr = k >> 3, k7 = k & 7;
        float bz = bcast8(y[tr], k7);      // z[k] (rows finalize high->low)
        float cm = (h < k7) ? A[tr][k] : 0.0f;  // owner & done rows: no-op
        y[tr] = fmaf(-cm, bz, y[tr]);
        #pragma unroll
        for (int q = 0; q < tr; ++q)
            y[q] = fmaf(-A[q][k], bz, y[q]);
    }
    // y[r] = z[8r + h]

    // ---- store z (dense 32B-segment pattern) ----
    float* zp = out + (size_t)b * CDIM * HWDIM + (size_t)h * HWDIM + pix;
    #pragma unroll
    for (int r = 0; r < 4; ++r) zp[(size_t)(r * 8) * HWDIM] = y[r];

    // ---- logdet: lacc identical across a pixel's 8 lanes; 3 xor-shuffles
    // reduce the wave's 8 pixel-groups; one atomic per wave. ----
    float v2 = lacc;
    v2 += __shfl_xor(v2, 8);
    v2 += __shfl_xor(v2, 16);
    v2 += __shfl_xor(v2, 32);
    if (lane == 0) {
        float add = -v2 * 0.69314718055994531f;  // ln2 * sum(log2|piv|)
        if (pix0 == 0) add += logdet[b];         // exactly one wave per b
        atomicAdd(&out[ZOFF + b], add);
    }
}

extern "C" void kernel_launch(void* const* d_in, const int* in_sizes, int n_in,
                              void* d_out, int out_size, void* d_ws, size_t ws_size,
                              hipStream_t stream) {
    const float* input  = (const float*)d_in[0];
    const float* weight = (const float*)d_in[1];
    const float* logdet = (const float*)d_in[2];
    float* out = (float*)d_out;

    solve_kernel<<<BDIM * (HWDIM / PPB), NTHREADS, 0, stream>>>(input, weight,
                                                                logdet, out);
}